// Round 6
// baseline (654.854 us; speedup 1.0000x reference)
//
#include <hip/hip_runtime.h>
#include <hip/hip_cooperative_groups.h>
#include <math.h>

namespace cg = cooperative_groups;

// B=16, S=1024, E=320, H=8, DH=40 -> M = 16384 rows.
// Single persistent cooperative kernel: 8 stages separated by grid.sync(),
// replacing 8 serial launches (~6 us gap each). Fallback: 8-launch path.

#define M_ROWS 16384

typedef float f32x4 __attribute__((ext_vector_type(4)));
typedef __bf16 bf16x8 __attribute__((ext_vector_type(8)));
typedef unsigned short ushort_t;

typedef const __attribute__((address_space(1))) void* gas_ptr;
typedef __attribute__((address_space(3))) void* las_ptr;

__device__ __forceinline__ unsigned int f2bf(float f) {
    union { float f; unsigned int u; } v; v.f = f;
    unsigned int u = v.u + 0x7FFFu + ((v.u >> 16) & 1u);   // RNE
    return u >> 16;
}
__device__ __forceinline__ float bf2f(ushort_t s) {
    union { unsigned int u; float f; } v; v.u = ((unsigned int)s) << 16;
    return v.f;
}

// ---------------------------------------------------------------------------
// GEMM core (verified round 2/3): BM=128, BK=64, 4 waves, mfma 16x16x32 bf16.
// BN=64 -> wave grid 2x2 (64x32/wave); BN=32 -> 4x1 (32x32/wave).
// LDS row-major [rows][64] bf16, unit-XOR swizzle by (row&7); global_load_lds
// dest linear, SOURCE column pre-swizzled (both-sides rule #21).
// ---------------------------------------------------------------------------
template<int BN>
__device__ __forceinline__ void gemm_core(
    int tx, int ty,
    const ushort_t* __restrict__ X1, const ushort_t* __restrict__ X2,
    int ksplit, int K, const ushort_t* __restrict__ W,
    char* smem, f32x4 (*acc)[2])
{
    constexpr int BM = 128, BK = 64;
    constexpr int WROWS = (BN == 64) ? 2 : 4;
    constexpr int WCOLS = 4 / WROWS;
    constexpr int WM = BM / WROWS;
    constexpr int WN = BN / WCOLS;   // 32
    constexpr int MF = WM / 16;
    constexpr int NF = WN / 16;      // 2

    ushort_t* As = (ushort_t*)smem;
    ushort_t* Bs = As + BM * BK;

    const int tid  = threadIdx.x;
    const int wave = tid >> 6;
    const int lane = tid & 63;
    const int m0 = ty * BM;
    const int n0 = tx * BN;
    const int wr = wave / WCOLS;
    const int wc = wave % WCOLS;
    const int sr = lane >> 3;
    const int su = lane & 7;

    for (int k0 = 0; k0 < K; k0 += BK) {
        #pragma unroll
        for (int i = 0; i < (BM * BK * 2) / 4096; ++i) {
            const int c = i * 4 + wave;
            const int r = c * 8 + sr;
            const int gk = k0 + (su ^ (r & 7)) * 8;
            const ushort_t* src;
            if (gk < ksplit) src = X1 + (size_t)(m0 + r) * ksplit + gk;
            else             src = X2 + (size_t)(m0 + r) * (K - ksplit) + (gk - ksplit);
            __builtin_amdgcn_global_load_lds((gas_ptr)src, (las_ptr)&As[c * 512], 16, 0, 0);
        }
        #pragma unroll
        for (int i = 0; i < (BN * BK * 2) / 4096; ++i) {
            const int c = i * 4 + wave;
            const int r = c * 8 + sr;
            const int gk = k0 + (su ^ (r & 7)) * 8;
            const ushort_t* src = W + (size_t)(n0 + r) * K + gk;
            __builtin_amdgcn_global_load_lds((gas_ptr)src, (las_ptr)&Bs[c * 512], 16, 0, 0);
        }
        __syncthreads();

        #pragma unroll
        for (int s = 0; s < 2; ++s) {
            bf16x8 a[MF], b[NF];
            #pragma unroll
            for (int mf = 0; mf < MF; ++mf) {
                const int r  = wr * WM + mf * 16 + (lane & 15);
                const int lu = (s * 4 + (lane >> 4)) ^ (r & 7);
                a[mf] = *reinterpret_cast<const bf16x8*>(&As[r * 64 + lu * 8]);
            }
            #pragma unroll
            for (int nf = 0; nf < NF; ++nf) {
                const int r  = wc * WN + nf * 16 + (lane & 15);
                const int lu = (s * 4 + (lane >> 4)) ^ (r & 7);
                b[nf] = *reinterpret_cast<const bf16x8*>(&Bs[r * 64 + lu * 8]);
            }
            #pragma unroll
            for (int mf = 0; mf < MF; ++mf)
                #pragma unroll
                for (int nf = 0; nf < NF; ++nf)
                    acc[mf][nf] = __builtin_amdgcn_mfma_f32_16x16x32_bf16(
                        a[mf], b[nf], acc[mf][nf], 0, 0, 0);
        }
        __syncthreads();
    }
}

template<int BN, bool RELU>
__device__ __forceinline__ void gemm_store(
    int tx, int ty, f32x4 (*acc)[2], const float* __restrict__ bias,
    float* __restrict__ outF, ushort_t* __restrict__ outB, int N)
{
    constexpr int WROWS = (BN == 64) ? 2 : 4;
    constexpr int WCOLS = 4 / WROWS;
    constexpr int WM = 128 / WROWS;
    constexpr int WN = BN / WCOLS;
    constexpr int MF = WM / 16;

    const int tid  = threadIdx.x;
    const int wave = tid >> 6;
    const int lane = tid & 63;
    const int wr = wave / WCOLS;
    const int wc = wave % WCOLS;

    #pragma unroll
    for (int nf = 0; nf < 2; ++nf) {
        const int gn = tx * BN + wc * WN + nf * 16 + (lane & 15);
        const float bv = bias[gn];
        #pragma unroll
        for (int mf = 0; mf < MF; ++mf) {
            #pragma unroll
            for (int i = 0; i < 4; ++i) {
                const int gm = ty * 128 + wr * WM + mf * 16 + (lane >> 4) * 4 + i;
                float v = acc[mf][nf][i] + bv;
                if (RELU) v = fmaxf(v, 0.f);
                if (outF) outF[(size_t)gm * N + gn] = v;
                if (outB) outB[(size_t)gm * N + gn] = (ushort_t)f2bf(v);
            }
        }
    }
}

template<int BN, bool RELU>
__device__ __forceinline__ void gemm_full(
    int bid, int ntx,
    const ushort_t* X1, const ushort_t* X2, int ksplit, int K,
    const ushort_t* W, const float* bias,
    float* outF, ushort_t* outB, int N, char* smem)
{
    const int tx = bid % ntx, ty = bid / ntx;
    constexpr int MF = (BN == 64) ? 4 : 2;
    f32x4 acc[MF][2];
    #pragma unroll
    for (int i = 0; i < MF; ++i) { acc[i][0] = (f32x4)0.f; acc[i][1] = (f32x4)0.f; }
    gemm_core<BN>(tx, ty, X1, X2, ksplit, K, W, smem, acc);
    gemm_store<BN, RELU>(tx, ty, acc, bias, outF, outB, N);
}

// --- attention over batch axis (per (s,h): 16x16 scores over DH=40) ---------
__device__ __forceinline__ void attn_dev(
    int ab, const ushort_t* __restrict__ qkv, ushort_t* __restrict__ ctx, char* smem)
{
    float* q_s = (float*)smem;            // [16][40]
    float* k_s = q_s + 16 * 40;
    float* v_s = k_s + 16 * 40;
    float* p_s = v_s + 16 * 40;           // [16][16]

    const int s   = ab >> 3;
    const int h   = ab & 7;
    const int tid = threadIdx.x;
    const int hb  = h * 40;

    for (int idx = tid; idx < 16 * 40; idx += 256) {
        int l = idx / 40, d = idx % 40;
        size_t row = (size_t)(l * 1024 + s) * 960;
        q_s[idx] = bf2f(qkv[row + hb + d]);
        k_s[idx] = bf2f(qkv[row + 320 + hb + d]);
        v_s[idx] = bf2f(qkv[row + 640 + hb + d]);
    }
    __syncthreads();

    {
        const int l = tid >> 4, m = tid & 15;
        float sc = 0.f;
        #pragma unroll
        for (int d = 0; d < 40; ++d) sc += q_s[l * 40 + d] * k_s[m * 40 + d];
        sc *= 0.15811388300841897f;   // 1/sqrt(40)
        float mx = sc;
        #pragma unroll
        for (int off = 1; off < 16; off <<= 1) mx = fmaxf(mx, __shfl_xor(mx, off, 16));
        float e = expf(sc - mx);
        float sum = e;
        #pragma unroll
        for (int off = 1; off < 16; off <<= 1) sum += __shfl_xor(sum, off, 16);
        p_s[l * 16 + m] = e / sum;
    }
    __syncthreads();

    for (int idx = tid; idx < 16 * 40; idx += 256) {
        int l = idx / 40, d = idx % 40;
        float acc = 0.f;
        #pragma unroll
        for (int m = 0; m < 16; ++m) acc += p_s[l * 16 + m] * v_s[m * 40 + d];
        ctx[(size_t)(l * 1024 + s) * 320 + hb + d] = (ushort_t)f2bf(acc);
    }
    __syncthreads();   // LDS reused by next persistent unit
}

// --- one wave per row, tiny N (1 or 3), K=160 -------------------------------
__device__ __forceinline__ void rowdot_dev(
    int row, const ushort_t* __restrict__ X, int K,
    const float* __restrict__ W, const float* __restrict__ bias,
    float* __restrict__ out, int N)
{
    const int lane = threadIdx.x & 63;
    for (int n = 0; n < N; ++n) {
        float s = 0.f;
        for (int j = lane; j < K; j += 64)
            s += bf2f(X[(size_t)row * K + j]) * W[(size_t)n * K + j];
        #pragma unroll
        for (int off = 32; off; off >>= 1) s += __shfl_down(s, off);
        if (lane == 0) out[(size_t)row * N + n] = s + bias[n];
    }
}

// ================================ mega ======================================

struct MegaArgs {
    // S0 conversions
    const float* csrc[10]; ushort_t* cdst[10]; int cstart[11]; int conv_total;
    // G1
    const ushort_t* xb; const ushort_t* Wcat;
    const float *fpb1, *bq, *bk, *bvv;
    ushort_t *t1b, *qkvb;
    // weights bf16
    const ushort_t *fpW1b, *fpW2b, *Wob, *mW1b, *pW1b, *pW2b;
    // fp32 biases / small weights
    const float *fpb2, *bo, *mb1, *pb1, *pb2;
    const float *mW2, *mb2, *pW3, *pb3;
    // outputs
    float *out_bb, *out_side, *out_cm, *out_ref;
    // intermediates
    ushort_t *bbB, *sideB, *ctxb, *aoB, *t2b, *c1, *t3, *c2;
    float* probF;
};

__device__ __forceinline__ void conv_unit(const MegaArgs& A, int u)
{
    int i = 0;
    #pragma unroll
    for (int t = 0; t < 10; ++t) if (u >= A.cstart[t + 1]) i = t + 1;
    const int idx = ((u - A.cstart[i]) * 256 + (int)threadIdx.x) * 4;
    float4 v = *reinterpret_cast<const float4*>(A.csrc[i] + idx);
    unsigned int lo = f2bf(v.x) | (f2bf(v.y) << 16);
    unsigned int hi = f2bf(v.z) | (f2bf(v.w) << 16);
    *reinterpret_cast<uint2*>(A.cdst[i] + idx) = make_uint2(lo, hi);
}

// G1 tile (BN=64): x -> [fp1(relu) | q | k | v], N=1280
__device__ __forceinline__ void g1_tile(const MegaArgs& A, int t, char* smem)
{
    const int tx = t % 20, ty = t / 20;
    f32x4 acc[4][2];
    #pragma unroll
    for (int i = 0; i < 4; ++i) { acc[i][0] = (f32x4)0.f; acc[i][1] = (f32x4)0.f; }
    gemm_core<64>(tx, ty, A.xb, A.xb, 320, 320, A.Wcat, smem, acc);

    const int tid = threadIdx.x, wave = tid >> 6, lane = tid & 63;
    const int wr = wave >> 1, wc = wave & 1;
    #pragma unroll
    for (int nf = 0; nf < 2; ++nf) {
        const int gn = tx * 64 + wc * 32 + nf * 16 + (lane & 15);
        float bv;
        if      (gn < 320) bv = A.fpb1[gn];
        else if (gn < 640) bv = A.bq[gn - 320];
        else if (gn < 960) bv = A.bk[gn - 640];
        else               bv = A.bvv[gn - 960];
        #pragma unroll
        for (int mf = 0; mf < 4; ++mf) {
            #pragma unroll
            for (int i = 0; i < 4; ++i) {
                const int gm = ty * 128 + wr * 64 + mf * 16 + (lane >> 4) * 4 + i;
                float v = acc[mf][nf][i] + bv;
                if (gn < 320) A.t1b [(size_t)gm * 320 + gn] = (ushort_t)f2bf(fmaxf(v, 0.f));
                else          A.qkvb[(size_t)gm * 960 + gn - 320] = (ushort_t)f2bf(v);
            }
        }
    }
}

// Stage bodies shared by mega + fallback kernels --------------------------
__device__ __forceinline__ void stage2_unit(const MegaArgs& A, int t, char* smem) {
    if (t < 640) gemm_full<64, false>(t, 5, A.t1b, A.t1b, 320, 320, A.fpW2b, A.fpb2, A.out_bb, A.bbB, 320, smem);
    else         attn_dev(t - 640, A.qkvb, A.ctxb, smem);
}
__device__ __forceinline__ void stage3_unit(const MegaArgs& A, int t, char* smem) {
    if (t < 640) gemm_full<64, false>(t, 5, A.ctxb, A.ctxb, 320, 320, A.Wob, A.bo, nullptr, A.aoB, 320, smem);
    else         gemm_full<64, true >(t - 640, 5, A.bbB, A.bbB, 320, 320, A.fpW1b, A.fpb1, nullptr, A.t2b, 320, smem);
}
__device__ __forceinline__ void stage4_unit(const MegaArgs& A, int t, char* smem) {
    if (t < 640) gemm_full<64, false>(t, 5, A.t2b, A.t2b, 320, 320, A.fpW2b, A.fpb2, A.out_side, A.sideB, 320, smem);
    else         gemm_full<32, true >(t - 640, 5, A.aoB, A.aoB, 320, 320, A.mW1b, A.mb1, nullptr, A.c1, 160, smem);
}
__device__ __forceinline__ void stage5_unit(const MegaArgs& A, int t, char* smem) {
    if (t < 640) gemm_full<64, true>(t, 5, A.bbB, A.sideB, 320, 640, A.pW1b, A.pb1, nullptr, A.t3, 320, smem);
    else         rowdot_dev((t - 640) * 4 + ((int)threadIdx.x >> 6), A.c1, 160, A.mW2, A.mb2, A.probF, 1);
}
__device__ __forceinline__ void stage6_unit(const MegaArgs& A, int t, char* smem) {
    if (t < 640) {
        gemm_full<32, true>(t, 5, A.t3, A.t3, 320, 320, A.pW2b, A.pb2, nullptr, A.c2, 160, smem);
    } else {
        const int row = t - 640;
        const float p = A.probF[row];
        reinterpret_cast<float4*>(A.out_cm + (size_t)row * 1024)[threadIdx.x] =
            make_float4(p, p, p, p);
    }
}

__global__ __launch_bounds__(256, 4) void mega(MegaArgs A)
{
    cg::grid_group g = cg::this_grid();
    __shared__ __align__(16) char smem[24 * 1024];
    const int nb = (int)gridDim.x;
    const int b0 = (int)blockIdx.x;

    for (int u = b0; u < A.conv_total; u += nb) conv_unit(A, u);
    g.sync();
    for (int t = b0; t < 2560; t += nb) g1_tile(A, t, smem);
    g.sync();
    for (int t = b0; t < 8832; t += nb) stage2_unit(A, t, smem);
    g.sync();
    for (int t = b0; t < 1280; t += nb) stage3_unit(A, t, smem);
    g.sync();
    for (int t = b0; t < 1280; t += nb) stage4_unit(A, t, smem);
    g.sync();
    for (int t = b0; t < 4736; t += nb) stage5_unit(A, t, smem);
    g.sync();
    for (int t = b0; t < 17024; t += nb) stage6_unit(A, t, smem);
    g.sync();
    for (int t = b0; t < 4096; t += nb)
        rowdot_dev(t * 4 + ((int)threadIdx.x >> 6), A.c2, 160, A.pW3, A.pb3, A.out_ref, 3);
}

// ------------------------- fallback (8-launch) kernels ----------------------
__global__ __launch_bounds__(256) void fb0(MegaArgs A) { conv_unit(A, blockIdx.x); }
__global__ __launch_bounds__(256) void fb1(MegaArgs A) {
    __shared__ __align__(16) char smem[24 * 1024];
    g1_tile(A, blockIdx.x, smem);
}
__global__ __launch_bounds__(256) void fb2(MegaArgs A) {
    __shared__ __align__(16) char smem[24 * 1024];
    stage2_unit(A, blockIdx.x, smem);
}
__global__ __launch_bounds__(256) void fb3(MegaArgs A) {
    __shared__ __align__(16) char smem[24 * 1024];
    stage3_unit(A, blockIdx.x, smem);
}
__global__ __launch_bounds__(256) void fb4(MegaArgs A) {
    __shared__ __align__(16) char smem[24 * 1024];
    stage4_unit(A, blockIdx.x, smem);
}
__global__ __launch_bounds__(256) void fb5(MegaArgs A) {
    __shared__ __align__(16) char smem[24 * 1024];
    stage5_unit(A, blockIdx.x, smem);
}
__global__ __launch_bounds__(256) void fb6(MegaArgs A) {
    __shared__ __align__(16) char smem[24 * 1024];
    stage6_unit(A, blockIdx.x, smem);
}
__global__ __launch_bounds__(256) void fb7(MegaArgs A) {
    rowdot_dev(blockIdx.x * 4 + ((int)threadIdx.x >> 6), A.c2, 160, A.pW3, A.pb3, A.out_ref, 3);
}

extern "C" void kernel_launch(void* const* d_in, const int* in_sizes, int n_in,
                              void* d_out, int out_size, void* d_ws, size_t ws_size,
                              hipStream_t stream)
{
    const float* x    = (const float*)d_in[0];
    const float* fpW1 = (const float*)d_in[1];
    const float* fpb1 = (const float*)d_in[2];
    const float* fpW2 = (const float*)d_in[3];
    const float* fpb2 = (const float*)d_in[4];
    const float* Wq   = (const float*)d_in[5];
    const float* bq   = (const float*)d_in[6];
    const float* Wk   = (const float*)d_in[7];
    const float* bk   = (const float*)d_in[8];
    const float* Wv   = (const float*)d_in[9];
    const float* bv   = (const float*)d_in[10];
    const float* Wo   = (const float*)d_in[11];
    const float* bo   = (const float*)d_in[12];
    const float* mW1  = (const float*)d_in[13];
    const float* mb1  = (const float*)d_in[14];
    const float* mW2  = (const float*)d_in[15];
    const float* mb2  = (const float*)d_in[16];
    const float* pW1  = (const float*)d_in[17];
    const float* pb1  = (const float*)d_in[18];
    const float* pW2  = (const float*)d_in[19];
    const float* pb2  = (const float*)d_in[20];
    const float* pW3  = (const float*)d_in[21];
    const float* pb3  = (const float*)d_in[22];

    float* out      = (float*)d_out;
    ushort_t* ws = (ushort_t*)d_ws;
    const size_t BUF = 5242880;
    ushort_t* xb    = ws;              // x bf16; later ctx; later c2 [M,160]
    ushort_t* t1b   = ws + 1 * BUF;    // fp1(x) relu; later t3 (pW1 out)
    ushort_t* bbB   = ws + 2 * BUF;
    ushort_t* sideB = ws + 3 * BUF;
    ushort_t* qkvb  = ws + 4 * BUF;    // [M,960] spans 3 BUFs; later aoB|t2b|c1
    ushort_t* wb    = ws + 7 * BUF;
    ushort_t* fpW1b = wb;              // Wcat = [fpW1|Wq|Wk|Wv] contiguous
    ushort_t* Wqb   = wb + 102400;
    ushort_t* Wkb   = wb + 204800;
    ushort_t* Wvb   = wb + 307200;
    ushort_t* fpW2b = wb + 409600;
    ushort_t* Wob   = wb + 512000;
    ushort_t* mW1b  = wb + 614400;
    ushort_t* pW1b  = wb + 665600;
    ushort_t* pW2b  = wb + 870400;
    float* probF = (float*)(ws + 7 * BUF + 921600);

    MegaArgs A;
    {
        const float* srcs[10] = {x, fpW1, Wq, Wk, Wv, fpW2, Wo, mW1, pW1, pW2};
        ushort_t*    dsts[10] = {xb, fpW1b, Wqb, Wkb, Wvb, fpW2b, Wob, mW1b, pW1b, pW2b};
        const int    nblk[10] = {5120, 100, 100, 100, 100, 100, 100, 50, 200, 50};
        int acc_blk = 0;
        for (int i = 0; i < 10; ++i) {
            A.csrc[i] = srcs[i]; A.cdst[i] = dsts[i];
            A.cstart[i] = acc_blk; acc_blk += nblk[i];
        }
        A.cstart[10] = acc_blk;
        A.conv_total = acc_blk;        // 6020
    }
    A.xb = xb; A.Wcat = wb;
    A.fpb1 = fpb1; A.bq = bq; A.bk = bk; A.bvv = bv;
    A.t1b = t1b; A.qkvb = qkvb;
    A.fpW1b = fpW1b; A.fpW2b = fpW2b; A.Wob = Wob;
    A.mW1b = mW1b; A.pW1b = pW1b; A.pW2b = pW2b;
    A.fpb2 = fpb2; A.bo = bo; A.mb1 = mb1; A.pb1 = pb1; A.pb2 = pb2;
    A.mW2 = mW2; A.mb2 = mb2; A.pW3 = pW3; A.pb3 = pb3;
    A.out_bb   = out;
    A.out_side = out + 5242880;
    A.out_cm   = out + 2 * 5242880;
    A.out_ref  = out + 2 * 5242880 + 16777216;
    A.bbB = bbB; A.sideB = sideB;
    A.ctxb = xb;                       // aliases (lifetimes disjoint, proven r3-5)
    A.aoB  = qkvb;
    A.t2b  = qkvb + BUF;
    A.c1   = qkvb + 2 * BUF;
    A.t3   = t1b;
    A.c2   = xb;
    A.probF = probF;

    // Cooperative grid: min(1024, occupancy * 256 CUs), multiple of 8
    int occ = 0;
    if (hipOccupancyMaxActiveBlocksPerMultiprocessor(
            &occ, (const void*)mega, 256, 0) != hipSuccess || occ < 1)
        occ = 2;
    int nb = occ * 256;
    if (nb > 1024) nb = 1024;
    nb &= ~7;
    if (nb < 8) nb = 8;

    void* kargs[] = { &A };
    hipError_t le = hipLaunchCooperativeKernel(
        (const void*)mega, dim3(nb), dim3(256), kargs, 0, stream);

    if (le != hipSuccess) {
        // fallback: the proven 8-launch sequence (identical device code)
        dim3 blk(256);
        fb0<<<dim3(A.conv_total), blk, 0, stream>>>(A);
        fb1<<<dim3(2560),  blk, 0, stream>>>(A);
        fb2<<<dim3(8832),  blk, 0, stream>>>(A);
        fb3<<<dim3(1280),  blk, 0, stream>>>(A);
        fb4<<<dim3(1280),  blk, 0, stream>>>(A);
        fb5<<<dim3(4736),  blk, 0, stream>>>(A);
        fb6<<<dim3(17024), blk, 0, stream>>>(A);
        fb7<<<dim3(4096),  blk, 0, stream>>>(A);
    }
}

// Round 7
// 172.545 us; speedup vs baseline: 3.7953x; 3.7953x over previous
//
#include <hip/hip_runtime.h>
#include <math.h>

// B=16, S=1024, E=320, H=8, DH=40 -> M = 16384 rows.
// All heavy layers bf16 MFMA. 7 launches via block-range megakernels.
// (Cooperative grid.sync measured ~100us/sync on gfx950 -- not used.)

#define M_ROWS 16384

typedef float f32x4 __attribute__((ext_vector_type(4)));
typedef __bf16 bf16x8 __attribute__((ext_vector_type(8)));
typedef unsigned short ushort_t;

typedef const __attribute__((address_space(1))) void* gas_ptr;
typedef __attribute__((address_space(3))) void* las_ptr;

__device__ __forceinline__ unsigned int f2bf(float f) {
    union { float f; unsigned int u; } v; v.f = f;
    unsigned int u = v.u + 0x7FFFu + ((v.u >> 16) & 1u);   // RNE
    return u >> 16;
}
__device__ __forceinline__ float bf2f(ushort_t s) {
    union { unsigned int u; float f; } v; v.u = ((unsigned int)s) << 16;
    return v.f;
}

// ---------------------------------------------------------------------------
// GEMM core (verified round 2/3): BM=128, BK=64, 4 waves, mfma 16x16x32 bf16.
// BN=64 -> wave grid 2x2 (64x32/wave); BN=32 -> 4x1 (32x32/wave).
// LDS row-major [rows][64] bf16, unit-XOR swizzle by (row&7); global_load_lds
// dest linear, SOURCE column pre-swizzled (both-sides rule #21).
// ---------------------------------------------------------------------------
template<int BN>
__device__ __forceinline__ void gemm_core(
    int tx, int ty,
    const ushort_t* __restrict__ X1, const ushort_t* __restrict__ X2,
    int ksplit, int K, const ushort_t* __restrict__ W,
    char* smem, f32x4 (*acc)[2])
{
    constexpr int BM = 128, BK = 64;
    constexpr int WROWS = (BN == 64) ? 2 : 4;
    constexpr int WCOLS = 4 / WROWS;
    constexpr int WM = BM / WROWS;
    constexpr int WN = BN / WCOLS;   // 32
    constexpr int MF = WM / 16;
    constexpr int NF = WN / 16;      // 2

    ushort_t* As = (ushort_t*)smem;
    ushort_t* Bs = As + BM * BK;

    const int tid  = threadIdx.x;
    const int wave = tid >> 6;
    const int lane = tid & 63;
    const int m0 = ty * BM;
    const int n0 = tx * BN;
    const int wr = wave / WCOLS;
    const int wc = wave % WCOLS;
    const int sr = lane >> 3;
    const int su = lane & 7;

    for (int k0 = 0; k0 < K; k0 += BK) {
        #pragma unroll
        for (int i = 0; i < (BM * BK * 2) / 4096; ++i) {
            const int c = i * 4 + wave;
            const int r = c * 8 + sr;
            const int gk = k0 + (su ^ (r & 7)) * 8;
            const ushort_t* src;
            if (gk < ksplit) src = X1 + (size_t)(m0 + r) * ksplit + gk;
            else             src = X2 + (size_t)(m0 + r) * (K - ksplit) + (gk - ksplit);
            __builtin_amdgcn_global_load_lds((gas_ptr)src, (las_ptr)&As[c * 512], 16, 0, 0);
        }
        #pragma unroll
        for (int i = 0; i < (BN * BK * 2) / 4096; ++i) {
            const int c = i * 4 + wave;
            const int r = c * 8 + sr;
            const int gk = k0 + (su ^ (r & 7)) * 8;
            const ushort_t* src = W + (size_t)(n0 + r) * K + gk;
            __builtin_amdgcn_global_load_lds((gas_ptr)src, (las_ptr)&Bs[c * 512], 16, 0, 0);
        }
        __syncthreads();

        #pragma unroll
        for (int s = 0; s < 2; ++s) {
            bf16x8 a[MF], b[NF];
            #pragma unroll
            for (int mf = 0; mf < MF; ++mf) {
                const int r  = wr * WM + mf * 16 + (lane & 15);
                const int lu = (s * 4 + (lane >> 4)) ^ (r & 7);
                a[mf] = *reinterpret_cast<const bf16x8*>(&As[r * 64 + lu * 8]);
            }
            #pragma unroll
            for (int nf = 0; nf < NF; ++nf) {
                const int r  = wc * WN + nf * 16 + (lane & 15);
                const int lu = (s * 4 + (lane >> 4)) ^ (r & 7);
                b[nf] = *reinterpret_cast<const bf16x8*>(&Bs[r * 64 + lu * 8]);
            }
            #pragma unroll
            for (int mf = 0; mf < MF; ++mf)
                #pragma unroll
                for (int nf = 0; nf < NF; ++nf)
                    acc[mf][nf] = __builtin_amdgcn_mfma_f32_16x16x32_bf16(
                        a[mf], b[nf], acc[mf][nf], 0, 0, 0);
        }
        __syncthreads();
    }
}

template<int BN, bool RELU>
__device__ __forceinline__ void gemm_store(
    int tx, int ty, f32x4 (*acc)[2], const float* __restrict__ bias,
    float* __restrict__ outF, ushort_t* __restrict__ outB, int N)
{
    constexpr int WROWS = (BN == 64) ? 2 : 4;
    constexpr int WCOLS = 4 / WROWS;
    constexpr int WM = 128 / WROWS;
    constexpr int WN = BN / WCOLS;
    constexpr int MF = WM / 16;

    const int tid  = threadIdx.x;
    const int wave = tid >> 6;
    const int lane = tid & 63;
    const int wr = wave / WCOLS;
    const int wc = wave % WCOLS;

    #pragma unroll
    for (int nf = 0; nf < 2; ++nf) {
        const int gn = tx * BN + wc * WN + nf * 16 + (lane & 15);
        const float bv = bias[gn];
        #pragma unroll
        for (int mf = 0; mf < MF; ++mf) {
            #pragma unroll
            for (int i = 0; i < 4; ++i) {
                const int gm = ty * 128 + wr * WM + mf * 16 + (lane >> 4) * 4 + i;
                float v = acc[mf][nf][i] + bv;
                if (RELU) v = fmaxf(v, 0.f);
                if (outF) outF[(size_t)gm * N + gn] = v;
                if (outB) outB[(size_t)gm * N + gn] = (ushort_t)f2bf(v);
            }
        }
    }
}

template<int BN, bool RELU>
__device__ __forceinline__ void gemm_full(
    int bid, int ntx,
    const ushort_t* X1, const ushort_t* X2, int ksplit, int K,
    const ushort_t* W, const float* bias,
    float* outF, ushort_t* outB, int N, char* smem)
{
    const int tx = bid % ntx, ty = bid / ntx;
    constexpr int MF = (BN == 64) ? 4 : 2;
    f32x4 acc[MF][2];
    #pragma unroll
    for (int i = 0; i < MF; ++i) { acc[i][0] = (f32x4)0.f; acc[i][1] = (f32x4)0.f; }
    gemm_core<BN>(tx, ty, X1, X2, ksplit, K, W, smem, acc);
    gemm_store<BN, RELU>(tx, ty, acc, bias, outF, outB, N);
}

// --- attention over batch axis (per (s,h): 16x16 scores over DH=40) ---------
// Softmax wave-parallel: width-16 __shfl_xor reductions, all 256 lanes live.
__device__ __forceinline__ void attn_dev(
    int ab, const ushort_t* __restrict__ qkv, ushort_t* __restrict__ ctx, char* smem)
{
    float* q_s = (float*)smem;            // [16][40]
    float* k_s = q_s + 16 * 40;
    float* v_s = k_s + 16 * 40;
    float* p_s = v_s + 16 * 40;           // [16][16]

    const int s   = ab >> 3;
    const int h   = ab & 7;
    const int tid = threadIdx.x;
    const int hb  = h * 40;

    for (int idx = tid; idx < 16 * 40; idx += 256) {
        int l = idx / 40, d = idx % 40;
        size_t row = (size_t)(l * 1024 + s) * 960;
        q_s[idx] = bf2f(qkv[row + hb + d]);
        k_s[idx] = bf2f(qkv[row + 320 + hb + d]);
        v_s[idx] = bf2f(qkv[row + 640 + hb + d]);
    }
    __syncthreads();

    {
        const int l = tid >> 4, m = tid & 15;
        float sc = 0.f;
        #pragma unroll
        for (int d = 0; d < 40; ++d) sc += q_s[l * 40 + d] * k_s[m * 40 + d];
        sc *= 0.15811388300841897f;   // 1/sqrt(40)
        float mx = sc;
        #pragma unroll
        for (int off = 1; off < 16; off <<= 1) mx = fmaxf(mx, __shfl_xor(mx, off, 16));
        float e = expf(sc - mx);
        float sum = e;
        #pragma unroll
        for (int off = 1; off < 16; off <<= 1) sum += __shfl_xor(sum, off, 16);
        p_s[l * 16 + m] = e / sum;
    }
    __syncthreads();

    for (int idx = tid; idx < 16 * 40; idx += 256) {
        int l = idx / 40, d = idx % 40;
        float acc = 0.f;
        #pragma unroll
        for (int m = 0; m < 16; ++m) acc += p_s[l * 16 + m] * v_s[m * 40 + d];
        ctx[(size_t)(l * 1024 + s) * 320 + hb + d] = (ushort_t)f2bf(acc);
    }
}

// --- one wave per row, tiny N (1 or 3), K=160 -------------------------------
__device__ __forceinline__ void rowdot_dev(
    int row, const ushort_t* __restrict__ X, int K,
    const float* __restrict__ W, const float* __restrict__ bias,
    float* __restrict__ out, int N)
{
    const int lane = threadIdx.x & 63;
    for (int n = 0; n < N; ++n) {
        float s = 0.f;
        for (int j = lane; j < K; j += 64)
            s += bf2f(X[(size_t)row * K + j]) * W[(size_t)n * K + j];
        #pragma unroll
        for (int off = 32; off; off >>= 1) s += __shfl_down(s, off);
        if (lane == 0) out[(size_t)row * N + n] = s + bias[n];
    }
}

// ================================ kernels ===================================

struct ConvDesc { const float* src; ushort_t* dst; };
struct ConvPack { ConvDesc d[6]; int start[7]; };

// L1: blocks [0,2560): G1 = x -> [fp1(relu) | q | k | v], BM=128 BN=64 BK=64,
//     A (x fp32) and B (Wcat fp32) reg-staged with inline RNE->bf16 and
//     dest-swizzled ds_write (write-swz == read-swz, rule #21).
//     XCD mapping: xcd=bid&7, panel-inner-tx -> each x row-panel (160 KB fp32)
//     is read by 20 consecutive blocks on ONE XCD -> L2-hot, HBM-fetched once.
//     Blocks [2560,3160): convert the 6 weight matrices later stages need.
__global__ __launch_bounds__(256) void k_g1(
    const float* __restrict__ xf,
    const float* __restrict__ fpW1, const float* __restrict__ Wq,
    const float* __restrict__ Wk, const float* __restrict__ Wv,
    const float* __restrict__ fpb1, const float* __restrict__ bq,
    const float* __restrict__ bk, const float* __restrict__ bvv,
    ushort_t* __restrict__ t1b, ushort_t* __restrict__ qkvb,
    ConvPack cp)
{
    constexpr int BM = 128, BK = 64;
    __shared__ __align__(16) ushort_t As[BM * BK];   // 16 KB
    __shared__ __align__(16) ushort_t Bs[64 * BK];   //  8 KB

    const int bid = blockIdx.x;
    const int tid = threadIdx.x;

    if (bid >= 2560) {   // weight-conversion tail
        const int cb = bid - 2560;
        int i = 0;
        #pragma unroll
        for (int t = 0; t < 6; ++t) if (cb >= cp.start[t + 1]) i = t + 1;
        const int idx = ((cb - cp.start[i]) * 256 + tid) * 4;
        float4 v = *reinterpret_cast<const float4*>(&cp.d[i].src[idx]);
        unsigned int lo = f2bf(v.x) | (f2bf(v.y) << 16);
        unsigned int hi = f2bf(v.z) | (f2bf(v.w) << 16);
        *reinterpret_cast<uint2*>(&cp.d[i].dst[idx]) = make_uint2(lo, hi);
        return;
    }

    const int xcd   = bid & 7;
    const int i0    = bid >> 3;            // 0..319
    const int panel = i0 / 20;             // 0..15 (x panel within XCD)
    const int tx    = i0 % 20;             // inner: 20 tx tiles share the panel
    const int ty    = xcd * 16 + panel;    // 0..127

    const int wave = tid >> 6, lane = tid & 63;
    const int m0 = ty * BM, n0 = tx * 64;
    const int wr = wave >> 1, wc = wave & 1;

    f32x4 acc[4][2];
    #pragma unroll
    for (int i = 0; i < 4; ++i) { acc[i][0] = (f32x4)0.f; acc[i][1] = (f32x4)0.f; }

    for (int k0 = 0; k0 < 320; k0 += BK) {
        // A tile: 128 rows x 8 units of 8 floats -> bf16x8, swizzled write
        #pragma unroll
        for (int i = 0; i < 4; ++i) {
            const int c = i * 256 + tid;          // 0..1023
            const int r = c >> 3, u = c & 7;
            const float* src = xf + (size_t)(m0 + r) * 320 + k0 + u * 8;
            float4 f0 = *reinterpret_cast<const float4*>(src);
            float4 f1 = *reinterpret_cast<const float4*>(src + 4);
            uint4 pk;
            pk.x = f2bf(f0.x) | (f2bf(f0.y) << 16);
            pk.y = f2bf(f0.z) | (f2bf(f0.w) << 16);
            pk.z = f2bf(f1.x) | (f2bf(f1.y) << 16);
            pk.w = f2bf(f1.z) | (f2bf(f1.w) << 16);
            *reinterpret_cast<uint4*>(&As[r * 64 + (u ^ (r & 7)) * 8]) = pk;
        }
        // B tile: rows n0..n0+63 of concat [fpW1|Wq|Wk|Wv] (fp32)
        #pragma unroll
        for (int i = 0; i < 2; ++i) {
            const int c = i * 256 + tid;          // 0..511
            const int r = c >> 3, u = c & 7;
            const int gn = n0 + r;
            const float* Wp; int off;
            if      (gn < 320) { Wp = fpW1; off = 0; }
            else if (gn < 640) { Wp = Wq;   off = 320; }
            else if (gn < 960) { Wp = Wk;   off = 640; }
            else               { Wp = Wv;   off = 960; }
            const float* src = Wp + (size_t)(gn - off) * 320 + k0 + u * 8;
            float4 f0 = *reinterpret_cast<const float4*>(src);
            float4 f1 = *reinterpret_cast<const float4*>(src + 4);
            uint4 pk;
            pk.x = f2bf(f0.x) | (f2bf(f0.y) << 16);
            pk.y = f2bf(f0.z) | (f2bf(f0.w) << 16);
            pk.z = f2bf(f1.x) | (f2bf(f1.y) << 16);
            pk.w = f2bf(f1.z) | (f2bf(f1.w) << 16);
            *reinterpret_cast<uint4*>(&Bs[r * 64 + (u ^ (r & 7)) * 8]) = pk;
        }
        __syncthreads();

        #pragma unroll
        for (int s = 0; s < 2; ++s) {
            bf16x8 a[4], b[2];
            #pragma unroll
            for (int mf = 0; mf < 4; ++mf) {
                const int r  = wr * 64 + mf * 16 + (lane & 15);
                const int lu = (s * 4 + (lane >> 4)) ^ (r & 7);
                a[mf] = *reinterpret_cast<const bf16x8*>(&As[r * 64 + lu * 8]);
            }
            #pragma unroll
            for (int nf = 0; nf < 2; ++nf) {
                const int r  = wc * 32 + nf * 16 + (lane & 15);
                const int lu = (s * 4 + (lane >> 4)) ^ (r & 7);
                b[nf] = *reinterpret_cast<const bf16x8*>(&Bs[r * 64 + lu * 8]);
            }
            #pragma unroll
            for (int mf = 0; mf < 4; ++mf)
                #pragma unroll
                for (int nf = 0; nf < 2; ++nf)
                    acc[mf][nf] = __builtin_amdgcn_mfma_f32_16x16x32_bf16(
                        a[mf], b[nf], acc[mf][nf], 0, 0, 0);
        }
        __syncthreads();
    }

    #pragma unroll
    for (int nf = 0; nf < 2; ++nf) {
        const int gn = n0 + wc * 32 + nf * 16 + (lane & 15);
        float bv;
        if      (gn < 320) bv = fpb1[gn];
        else if (gn < 640) bv = bq[gn - 320];
        else if (gn < 960) bv = bk[gn - 640];
        else               bv = bvv[gn - 960];
        #pragma unroll
        for (int mf = 0; mf < 4; ++mf) {
            #pragma unroll
            for (int i = 0; i < 4; ++i) {
                const int gm = m0 + wr * 64 + mf * 16 + (lane >> 4) * 4 + i;
                float v = acc[mf][nf][i] + bv;
                if (gn < 320) t1b [(size_t)gm * 320 + gn] = (ushort_t)f2bf(fmaxf(v, 0.f));
                else          qkvb[(size_t)gm * 960 + gn - 320] = (ushort_t)f2bf(v);
            }
        }
    }
}

// L2: blocks [0,640) G2 (t1b -> fp2 -> bb), [640,8832) attention (qkv -> ctx)
__global__ __launch_bounds__(256) void k_g2_attn(
    const ushort_t* __restrict__ t1b, const ushort_t* __restrict__ fpW2b,
    const float* __restrict__ fpb2, float* __restrict__ out_bb,
    ushort_t* __restrict__ bbB,
    const ushort_t* __restrict__ qkvb, ushort_t* __restrict__ ctxb)
{
    __shared__ __align__(16) char smem[24 * 1024];
    const int bid = blockIdx.x;
    if (bid < 640) gemm_full<64, false>(bid, 5, t1b, t1b, 320, 320, fpW2b, fpb2, out_bb, bbB, 320, smem);
    else           attn_dev(bid - 640, qkvb, ctxb, smem);
}

// L3: blocks [0,640) G3 (ctx -> Wo -> attn_out), [640,1280) G4 (bb -> fp1 relu)
__global__ __launch_bounds__(256) void k_g3_g4(
    const ushort_t* __restrict__ ctxb, const ushort_t* __restrict__ Wob,
    const float* __restrict__ bo, ushort_t* __restrict__ aoB,
    const ushort_t* __restrict__ bbB, const ushort_t* __restrict__ fpW1b,
    const float* __restrict__ fpb1, ushort_t* __restrict__ t2b)
{
    __shared__ __align__(16) char smem[24 * 1024];
    const int bid = blockIdx.x;
    if (bid < 640) gemm_full<64, false>(bid, 5, ctxb, ctxb, 320, 320, Wob, bo, nullptr, aoB, 320, smem);
    else           gemm_full<64, true >(bid - 640, 5, bbB, bbB, 320, 320, fpW1b, fpb1, nullptr, t2b, 320, smem);
}

// L4: blocks [0,640) G5 (t2 -> fp2 -> side), [640,1280) G6 (attn_out -> mW1 relu)
__global__ __launch_bounds__(256) void k_g5_g6(
    const ushort_t* __restrict__ t2b, const ushort_t* __restrict__ fpW2b,
    const float* __restrict__ fpb2, float* __restrict__ out_side,
    ushort_t* __restrict__ sideB,
    const ushort_t* __restrict__ aoB, const ushort_t* __restrict__ mW1b,
    const float* __restrict__ mb1, ushort_t* __restrict__ c1)
{
    __shared__ __align__(16) char smem[24 * 1024];
    const int bid = blockIdx.x;
    if (bid < 640) gemm_full<64, false>(bid, 5, t2b, t2b, 320, 320, fpW2b, fpb2, out_side, sideB, 320, smem);
    else           gemm_full<32, true >(bid - 640, 5, aoB, aoB, 320, 320, mW1b, mb1, nullptr, c1, 160, smem);
}

// L5: blocks [0,640) G7 ([bb|side] -> pW1 relu, K=640), [640,4736) rowdot -> prob
__global__ __launch_bounds__(256) void k_g7_rd(
    const ushort_t* __restrict__ bbB, const ushort_t* __restrict__ sideB,
    const ushort_t* __restrict__ pW1b, const float* __restrict__ pb1,
    ushort_t* __restrict__ t3,
    const ushort_t* __restrict__ c1, const float* __restrict__ mW2,
    const float* __restrict__ mb2, float* __restrict__ probF)
{
    __shared__ __align__(16) char smem[24 * 1024];
    const int bid = blockIdx.x;
    if (bid < 640) gemm_full<64, true>(bid, 5, bbB, sideB, 320, 640, pW1b, pb1, nullptr, t3, 320, smem);
    else           rowdot_dev((bid - 640) * 4 + ((int)threadIdx.x >> 6), c1, 160, mW2, mb2, probF, 1);
}

// L6: blocks [0,640) G8 (t3 -> pW2 relu, N=160), [640,17024) contact broadcast
__global__ __launch_bounds__(256) void k_g8_ct(
    const ushort_t* __restrict__ t3, const ushort_t* __restrict__ pW2b,
    const float* __restrict__ pb2, ushort_t* __restrict__ c2,
    const float* __restrict__ probF, float* __restrict__ out_cm)
{
    __shared__ __align__(16) char smem[24 * 1024];
    const int bid = blockIdx.x;
    if (bid < 640) {
        gemm_full<32, true>(bid, 5, t3, t3, 320, 320, pW2b, pb2, nullptr, c2, 160, smem);
    } else {
        const int row = bid - 640;
        const float p = probF[row];
        reinterpret_cast<float4*>(out_cm + (size_t)row * 1024)[threadIdx.x] =
            make_float4(p, p, p, p);
    }
}

// L7: rowdot c2 -> refined [M,3]
__global__ __launch_bounds__(256) void k_rd3(
    const ushort_t* __restrict__ c2, const float* __restrict__ pW3,
    const float* __restrict__ pb3, float* __restrict__ out_ref)
{
    rowdot_dev(blockIdx.x * 4 + ((int)threadIdx.x >> 6), c2, 160, pW3, pb3, out_ref, 3);
}

extern "C" void kernel_launch(void* const* d_in, const int* in_sizes, int n_in,
                              void* d_out, int out_size, void* d_ws, size_t ws_size,
                              hipStream_t stream)
{
    const float* x    = (const float*)d_in[0];
    const float* fpW1 = (const float*)d_in[1];
    const float* fpb1 = (const float*)d_in[2];
    const float* fpW2 = (const float*)d_in[3];
    const float* fpb2 = (const float*)d_in[4];
    const float* Wq   = (const float*)d_in[5];
    const float* bq   = (const float*)d_in[6];
    const float* Wk   = (const float*)d_in[7];
    const float* bk   = (const float*)d_in[8];
    const float* Wv   = (const float*)d_in[9];
    const float* bv   = (const float*)d_in[10];
    const float* Wo   = (const float*)d_in[11];
    const float* bo   = (const float*)d_in[12];
    const float* mW1  = (const float*)d_in[13];
    const float* mb1  = (const float*)d_in[14];
    const float* mW2  = (const float*)d_in[15];
    const float* mb2  = (const float*)d_in[16];
    const float* pW1  = (const float*)d_in[17];
    const float* pb1  = (const float*)d_in[18];
    const float* pW2  = (const float*)d_in[19];
    const float* pb2  = (const float*)d_in[20];
    const float* pW3  = (const float*)d_in[21];
    const float* pb3  = (const float*)d_in[22];

    float* out      = (float*)d_out;
    float* out_bb   = out;
    float* out_side = out + 5242880;
    float* out_cm   = out + 2 * 5242880;
    float* out_ref  = out + 2 * 5242880 + 16777216;

    ushort_t* ws = (ushort_t*)d_ws;
    const size_t BUF = 5242880;
    ushort_t* ctxb  = ws;              // ctx after attn; later c2 [M,160]
    ushort_t* t1b   = ws + 1 * BUF;    // fp1(x) relu; later t3 (pW1 out)
    ushort_t* bbB   = ws + 2 * BUF;
    ushort_t* sideB = ws + 3 * BUF;
    ushort_t* qkvb  = ws + 4 * BUF;    // [M,960] spans 3 BUFs; later aoB|t2b|c1
    ushort_t* wb    = ws + 7 * BUF;    // bf16 weights (conv'd in k_g1 tail)
    ushort_t* fpW1b = wb;              // 102400
    ushort_t* fpW2b = wb + 102400;     // 102400
    ushort_t* Wob   = wb + 204800;     // 102400
    ushort_t* mW1b  = wb + 307200;     // 51200
    ushort_t* pW1b  = wb + 358400;     // 204800
    ushort_t* pW2b  = wb + 563200;     // 51200
    float* probF = (float*)(ws + 7 * BUF + 655360);   // 16384 fp32

    ushort_t* aoB  = qkvb;             // aliases (lifetimes disjoint)
    ushort_t* t2b  = qkvb + BUF;
    ushort_t* c1   = qkvb + 2 * BUF;
    ushort_t* t3   = t1b;
    ushort_t* c2   = ctxb;

    dim3 blk(256);

    ConvPack cp;
    const float* srcs[6] = {fpW1, fpW2, Wo, mW1, pW1, pW2};
    ushort_t*    dsts[6] = {fpW1b, fpW2b, Wob, mW1b, pW1b, pW2b};
    const int    nblk[6] = {100, 100, 100, 50, 200, 50};
    int acc_blk = 0;
    for (int i = 0; i < 6; ++i) {
        cp.d[i].src = srcs[i]; cp.d[i].dst = dsts[i];
        cp.start[i] = acc_blk; acc_blk += nblk[i];
    }
    cp.start[6] = acc_blk;   // 600

    // L1: G1 (2560 blocks, fp32 in, XCD-panel mapping) + weight conv (600)
    k_g1<<<dim3(2560 + acc_blk), blk, 0, stream>>>(
        x, fpW1, Wq, Wk, Wv, fpb1, bq, bk, bv, t1b, qkvb, cp);
    // L2: G2 (backbone) || attention
    k_g2_attn<<<dim3(8832), blk, 0, stream>>>(t1b, fpW2b, fpb2, out_bb, bbB, qkvb, ctxb);
    // L3: G3 (Wo proj) || G4 (fp1(bb))
    k_g3_g4<<<dim3(1280), blk, 0, stream>>>(ctxb, Wob, bo, aoB, bbB, fpW1b, fpb1, t2b);
    // L4: G5 (fp2 -> side) || G6 (mW1, N=160)
    k_g5_g6<<<dim3(1280), blk, 0, stream>>>(t2b, fpW2b, fpb2, out_side, sideB, aoB, mW1b, mb1, c1);
    // L5: G7 (pW1, K=640) || rowdot (mW2 -> prob)
    k_g7_rd<<<dim3(4736), blk, 0, stream>>>(bbB, sideB, pW1b, pb1, t3, c1, mW2, mb2, probF);
    // L6: G8 (pW2, N=160) || contact broadcast
    k_g8_ct<<<dim3(17024), blk, 0, stream>>>(t3, pW2b, pb2, c2, probF, out_cm);
    // L7: rowdot (pW3 -> refined)
    k_rd3<<<dim3(4096), blk, 0, stream>>>(c2, pW3, pb3, out_ref);
}

// Round 8
// 162.461 us; speedup vs baseline: 4.0308x; 1.0621x over previous
//
#include <hip/hip_runtime.h>
#include <math.h>

// B=16, S=1024, E=320, H=8, DH=40 -> M = 16384 rows.
// bf16 MFMA everywhere. 5 launches:
//   L0 conv -> L1 G1(fp1|q|k|v) -> L2 {G2(bb) || attn} ->
//   L3 {fusedB(bb->t2->side) || G3(Wo)} -> L4 {fusedC(pW1->pW2->pW3) || fusedD(mW1->mW2->contact)}
// Fused chains keep the intermediate 64-row panel in LDS (verified As layout),
// final small GEMM outputs stay in registers (shfl-reduced).

#define M_ROWS 16384

typedef float f32x4 __attribute__((ext_vector_type(4)));
typedef __bf16 bf16x8 __attribute__((ext_vector_type(8)));
typedef unsigned short ushort_t;

typedef const __attribute__((address_space(1))) void* gas_ptr;
typedef __attribute__((address_space(3))) void* las_ptr;

__device__ __forceinline__ unsigned int f2bf(float f) {
    union { float f; unsigned int u; } v; v.f = f;
    unsigned int u = v.u + 0x7FFFu + ((v.u >> 16) & 1u);   // RNE
    return u >> 16;
}
__device__ __forceinline__ float bf2f(ushort_t s) {
    union { unsigned int u; float f; } v; v.u = ((unsigned int)s) << 16;
    return v.f;
}

// ---------------------------------------------------------------------------
// GEMM core (verified r2/r3): BM=128, BK=64, 4 waves, mfma 16x16x32 bf16.
// LDS row-major [rows][64] bf16, unit-XOR swizzle by (row&7); global_load_lds
// dest linear, SOURCE column pre-swizzled (both-sides rule #21).
// ---------------------------------------------------------------------------
template<int BN>
__device__ __forceinline__ void gemm_core(
    int tx, int ty,
    const ushort_t* __restrict__ X1, const ushort_t* __restrict__ X2,
    int ksplit, int K, const ushort_t* __restrict__ W,
    char* smem, f32x4 (*acc)[2])
{
    constexpr int BM = 128, BK = 64;
    constexpr int WROWS = (BN == 64) ? 2 : 4;
    constexpr int WCOLS = 4 / WROWS;
    constexpr int WM = BM / WROWS;
    constexpr int WN = BN / WCOLS;   // 32
    constexpr int MF = WM / 16;
    constexpr int NF = WN / 16;      // 2

    ushort_t* As = (ushort_t*)smem;
    ushort_t* Bs = As + BM * BK;

    const int tid  = threadIdx.x;
    const int wave = tid >> 6;
    const int lane = tid & 63;
    const int m0 = ty * BM;
    const int n0 = tx * BN;
    const int wr = wave / WCOLS;
    const int wc = wave % WCOLS;
    const int sr = lane >> 3;
    const int su = lane & 7;

    for (int k0 = 0; k0 < K; k0 += BK) {
        #pragma unroll
        for (int i = 0; i < (BM * BK * 2) / 4096; ++i) {
            const int c = i * 4 + wave;
            const int r = c * 8 + sr;
            const int gk = k0 + (su ^ (r & 7)) * 8;
            const ushort_t* src;
            if (gk < ksplit) src = X1 + (size_t)(m0 + r) * ksplit + gk;
            else             src = X2 + (size_t)(m0 + r) * (K - ksplit) + (gk - ksplit);
            __builtin_amdgcn_global_load_lds((gas_ptr)src, (las_ptr)&As[c * 512], 16, 0, 0);
        }
        #pragma unroll
        for (int i = 0; i < (BN * BK * 2) / 4096; ++i) {
            const int c = i * 4 + wave;
            const int r = c * 8 + sr;
            const int gk = k0 + (su ^ (r & 7)) * 8;
            const ushort_t* src = W + (size_t)(n0 + r) * K + gk;
            __builtin_amdgcn_global_load_lds((gas_ptr)src, (las_ptr)&Bs[c * 512], 16, 0, 0);
        }
        __syncthreads();

        #pragma unroll
        for (int s = 0; s < 2; ++s) {
            bf16x8 a[MF], b[NF];
            #pragma unroll
            for (int mf = 0; mf < MF; ++mf) {
                const int r  = wr * WM + mf * 16 + (lane & 15);
                const int lu = (s * 4 + (lane >> 4)) ^ (r & 7);
                a[mf] = *reinterpret_cast<const bf16x8*>(&As[r * 64 + lu * 8]);
            }
            #pragma unroll
            for (int nf = 0; nf < NF; ++nf) {
                const int r  = wc * WN + nf * 16 + (lane & 15);
                const int lu = (s * 4 + (lane >> 4)) ^ (r & 7);
                b[nf] = *reinterpret_cast<const bf16x8*>(&Bs[r * 64 + lu * 8]);
            }
            #pragma unroll
            for (int mf = 0; mf < MF; ++mf)
                #pragma unroll
                for (int nf = 0; nf < NF; ++nf)
                    acc[mf][nf] = __builtin_amdgcn_mfma_f32_16x16x32_bf16(
                        a[mf], b[nf], acc[mf][nf], 0, 0, 0);
        }
        __syncthreads();
    }
}

template<int BN, bool RELU>
__device__ __forceinline__ void gemm_store(
    int tx, int ty, f32x4 (*acc)[2], const float* __restrict__ bias,
    float* __restrict__ outF, ushort_t* __restrict__ outB, int N)
{
    constexpr int WROWS = (BN == 64) ? 2 : 4;
    constexpr int WCOLS = 4 / WROWS;
    constexpr int WM = 128 / WROWS;
    constexpr int WN = BN / WCOLS;
    constexpr int MF = WM / 16;

    const int tid  = threadIdx.x;
    const int wave = tid >> 6;
    const int lane = tid & 63;
    const int wr = wave / WCOLS;
    const int wc = wave % WCOLS;

    #pragma unroll
    for (int nf = 0; nf < 2; ++nf) {
        const int gn = tx * BN + wc * WN + nf * 16 + (lane & 15);
        const float bv = bias[gn];
        #pragma unroll
        for (int mf = 0; mf < MF; ++mf) {
            #pragma unroll
            for (int i = 0; i < 4; ++i) {
                const int gm = ty * 128 + wr * WM + mf * 16 + (lane >> 4) * 4 + i;
                float v = acc[mf][nf][i] + bv;
                if (RELU) v = fmaxf(v, 0.f);
                if (outF) outF[(size_t)gm * N + gn] = v;
                if (outB) outB[(size_t)gm * N + gn] = (ushort_t)f2bf(v);
            }
        }
    }
}

template<int BN, bool RELU>
__device__ __forceinline__ void gemm_full(
    int bid, int ntx,
    const ushort_t* X1, const ushort_t* X2, int ksplit, int K,
    const ushort_t* W, const float* bias,
    float* outF, ushort_t* outB, int N, char* smem)
{
    const int tx = bid % ntx, ty = bid / ntx;
    constexpr int MF = (BN == 64) ? 4 : 2;
    f32x4 acc[MF][2];
    #pragma unroll
    for (int i = 0; i < MF; ++i) { acc[i][0] = (f32x4)0.f; acc[i][1] = (f32x4)0.f; }
    gemm_core<BN>(tx, ty, X1, X2, ksplit, K, W, smem, acc);
    gemm_store<BN, RELU>(tx, ty, acc, bias, outF, outB, N);
}

// --- attention over batch axis (per (s,h): 16x16 scores over DH=40) ---------
__device__ __forceinline__ void attn_dev(
    int ab, const ushort_t* __restrict__ qkv, ushort_t* __restrict__ ctx, char* smem)
{
    float* q_s = (float*)smem;            // [16][40]
    float* k_s = q_s + 16 * 40;
    float* v_s = k_s + 16 * 40;
    float* p_s = v_s + 16 * 40;           // [16][16]

    const int s   = ab >> 3;
    const int h   = ab & 7;
    const int tid = threadIdx.x;
    const int hb  = h * 40;

    for (int idx = tid; idx < 16 * 40; idx += 256) {
        int l = idx / 40, d = idx % 40;
        size_t row = (size_t)(l * 1024 + s) * 960;
        q_s[idx] = bf2f(qkv[row + hb + d]);
        k_s[idx] = bf2f(qkv[row + 320 + hb + d]);
        v_s[idx] = bf2f(qkv[row + 640 + hb + d]);
    }
    __syncthreads();

    {
        const int l = tid >> 4, m = tid & 15;
        float sc = 0.f;
        #pragma unroll
        for (int d = 0; d < 40; ++d) sc += q_s[l * 40 + d] * k_s[m * 40 + d];
        sc *= 0.15811388300841897f;   // 1/sqrt(40)
        float mx = sc;
        #pragma unroll
        for (int off = 1; off < 16; off <<= 1) mx = fmaxf(mx, __shfl_xor(mx, off, 16));
        float e = expf(sc - mx);
        float sum = e;
        #pragma unroll
        for (int off = 1; off < 16; off <<= 1) sum += __shfl_xor(sum, off, 16);
        p_s[l * 16 + m] = e / sum;
    }
    __syncthreads();

    for (int idx = tid; idx < 16 * 40; idx += 256) {
        int l = idx / 40, d = idx % 40;
        float acc = 0.f;
        #pragma unroll
        for (int m = 0; m < 16; ++m) acc += p_s[l * 16 + m] * v_s[m * 40 + d];
        ctx[(size_t)(l * 1024 + s) * 320 + hb + d] = (ushort_t)f2bf(acc);
    }
}

// ============================ fused panel kernels ===========================
// 64-row panels, 4 waves. 64x64 output tiles use a 2x2 wave grid (WM=WN=32);
// 32-col tiles use 4x1 (WM=16, WN=32). Panel LDS tiles use the SAME
// [row][64]-with-(row&7)-XOR layout as As, so fragment reads are identical.

// stage a 64x64 bf16 tile from global (swizzled source) via global_load_lds
__device__ __forceinline__ void stage64(
    const ushort_t* __restrict__ src, int row0, int ldk, int k0,
    ushort_t* dst, int wave, int sr, int su)
{
    #pragma unroll
    for (int i = 0; i < 2; ++i) {
        const int c = i * 4 + wave;
        const int r = c * 8 + sr;
        const int gk = k0 + (su ^ (r & 7)) * 8;
        __builtin_amdgcn_global_load_lds(
            (gas_ptr)(src + (size_t)(row0 + r) * ldk + gk),
            (las_ptr)&dst[c * 512], 16, 0, 0);
    }
}
// stage a 32x64 bf16 tile (4 chunks, one per wave)
__device__ __forceinline__ void stage32(
    const ushort_t* __restrict__ src, int row0, int ldk, int k0,
    ushort_t* dst, int wave, int sr, int su)
{
    const int r = wave * 8 + sr;
    const int gk = k0 + (su ^ (r & 7)) * 8;
    __builtin_amdgcn_global_load_lds(
        (gas_ptr)(src + (size_t)(row0 + r) * ldk + gk),
        (las_ptr)&dst[wave * 512], 16, 0, 0);
}

// fusedB: t2 = relu(fp1 . bb) (LDS panel) ; side = fp2 . t2 -> fp32 + bf16
__device__ void fusedB_dev(
    int panel, const ushort_t* __restrict__ bbB,
    const ushort_t* __restrict__ fpW1b, const float* __restrict__ fpb1,
    const ushort_t* __restrict__ fpW2b, const float* __restrict__ fpb2,
    float* __restrict__ out_side, ushort_t* __restrict__ sideB, char* smem)
{
    ushort_t* tpan = (ushort_t*)smem;       // 5 ktiles x [64][64] = 40 KB
    ushort_t* As   = tpan + 5 * 4096;       // 8 KB
    ushort_t* Bs   = As + 4096;             // 8 KB

    const int tid = threadIdx.x, wave = tid >> 6, lane = tid & 63;
    const int row0 = panel * 64;
    const int wr = wave >> 1, wc = wave & 1;
    const int sr = lane >> 3, su = lane & 7;

    // phase 1: t2 panel
    for (int nb = 0; nb < 5; ++nb) {
        f32x4 acc[2][2];
        acc[0][0] = acc[0][1] = acc[1][0] = acc[1][1] = (f32x4)0.f;
        for (int k0 = 0; k0 < 320; k0 += 64) {
            stage64(bbB,   row0,    320, k0, As, wave, sr, su);
            stage64(fpW1b, nb * 64, 320, k0, Bs, wave, sr, su);
            __syncthreads();
            #pragma unroll
            for (int s = 0; s < 2; ++s) {
                bf16x8 a[2], b[2];
                #pragma unroll
                for (int mf = 0; mf < 2; ++mf) {
                    const int r  = wr * 32 + mf * 16 + (lane & 15);
                    const int lu = (s * 4 + (lane >> 4)) ^ (r & 7);
                    a[mf] = *reinterpret_cast<const bf16x8*>(&As[r * 64 + lu * 8]);
                }
                #pragma unroll
                for (int nf = 0; nf < 2; ++nf) {
                    const int r  = wc * 32 + nf * 16 + (lane & 15);
                    const int lu = (s * 4 + (lane >> 4)) ^ (r & 7);
                    b[nf] = *reinterpret_cast<const bf16x8*>(&Bs[r * 64 + lu * 8]);
                }
                #pragma unroll
                for (int mf = 0; mf < 2; ++mf)
                    #pragma unroll
                    for (int nf = 0; nf < 2; ++nf)
                        acc[mf][nf] = __builtin_amdgcn_mfma_f32_16x16x32_bf16(
                            a[mf], b[nf], acc[mf][nf], 0, 0, 0);
            }
            __syncthreads();
        }
        // write tile nb into tpan (relu + bias), swizzled like As
        #pragma unroll
        for (int nf = 0; nf < 2; ++nf) {
            const int col = wc * 32 + nf * 16 + (lane & 15);
            const float bv = fpb1[nb * 64 + col];
            #pragma unroll
            for (int mf = 0; mf < 2; ++mf) {
                #pragma unroll
                for (int i = 0; i < 4; ++i) {
                    const int row = wr * 32 + mf * 16 + (lane >> 4) * 4 + i;
                    float v = fmaxf(acc[mf][nf][i] + bv, 0.f);
                    const int u = col >> 3;
                    tpan[nb * 4096 + row * 64 + ((u ^ (row & 7)) * 8) + (col & 7)]
                        = (ushort_t)f2bf(v);
                }
            }
        }
        __syncthreads();
    }

    // phase 2: side = t2 . fp2
    for (int nb = 0; nb < 5; ++nb) {
        f32x4 acc[2][2];
        acc[0][0] = acc[0][1] = acc[1][0] = acc[1][1] = (f32x4)0.f;
        for (int kt = 0; kt < 5; ++kt) {
            stage64(fpW2b, nb * 64, 320, kt * 64, Bs, wave, sr, su);
            __syncthreads();
            #pragma unroll
            for (int s = 0; s < 2; ++s) {
                bf16x8 a[2], b[2];
                #pragma unroll
                for (int mf = 0; mf < 2; ++mf) {
                    const int r  = wr * 32 + mf * 16 + (lane & 15);
                    const int lu = (s * 4 + (lane >> 4)) ^ (r & 7);
                    a[mf] = *reinterpret_cast<const bf16x8*>(&tpan[kt * 4096 + r * 64 + lu * 8]);
                }
                #pragma unroll
                for (int nf = 0; nf < 2; ++nf) {
                    const int r  = wc * 32 + nf * 16 + (lane & 15);
                    const int lu = (s * 4 + (lane >> 4)) ^ (r & 7);
                    b[nf] = *reinterpret_cast<const bf16x8*>(&Bs[r * 64 + lu * 8]);
                }
                #pragma unroll
                for (int mf = 0; mf < 2; ++mf)
                    #pragma unroll
                    for (int nf = 0; nf < 2; ++nf)
                        acc[mf][nf] = __builtin_amdgcn_mfma_f32_16x16x32_bf16(
                            a[mf], b[nf], acc[mf][nf], 0, 0, 0);
            }
            __syncthreads();
        }
        #pragma unroll
        for (int nf = 0; nf < 2; ++nf) {
            const int gn = nb * 64 + wc * 32 + nf * 16 + (lane & 15);
            const float bv = fpb2[gn];
            #pragma unroll
            for (int mf = 0; mf < 2; ++mf) {
                #pragma unroll
                for (int i = 0; i < 4; ++i) {
                    const int gm = row0 + wr * 32 + mf * 16 + (lane >> 4) * 4 + i;
                    float v = acc[mf][nf][i] + bv;
                    out_side[(size_t)gm * 320 + gn] = v;
                    sideB[(size_t)gm * 320 + gn] = (ushort_t)f2bf(v);
                }
            }
        }
    }
}

// fusedC: t3 = relu(pW1 . [bb|side]) (LDS) ; c2 = relu(pW2 . t3) in regs ;
//         refined = c2 . pW3 + pb3 via width-16 shfl reduce
__device__ void fusedC_dev(
    int panel, const ushort_t* __restrict__ bbB, const ushort_t* __restrict__ sideB,
    const ushort_t* __restrict__ pW1b, const float* __restrict__ pb1,
    const ushort_t* __restrict__ pW2b, const float* __restrict__ pb2,
    const float* __restrict__ pW3, const float* __restrict__ pb3,
    float* __restrict__ out_ref, char* smem)
{
    ushort_t* tpan = (ushort_t*)smem;       // 40 KB
    ushort_t* As   = tpan + 5 * 4096;
    ushort_t* Bs   = As + 4096;

    const int tid = threadIdx.x, wave = tid >> 6, lane = tid & 63;
    const int row0 = panel * 64;
    const int wr = wave >> 1, wc = wave & 1;
    const int sr = lane >> 3, su = lane & 7;

    // phase 1: t3 panel (K=640 dual input)
    for (int nb = 0; nb < 5; ++nb) {
        f32x4 acc[2][2];
        acc[0][0] = acc[0][1] = acc[1][0] = acc[1][1] = (f32x4)0.f;
        for (int k0 = 0; k0 < 640; k0 += 64) {
            // dual-source A stage
            #pragma unroll
            for (int i = 0; i < 2; ++i) {
                const int c = i * 4 + wave;
                const int r = c * 8 + sr;
                const int gk = k0 + (su ^ (r & 7)) * 8;
                const ushort_t* src = (gk < 320)
                    ? bbB   + (size_t)(row0 + r) * 320 + gk
                    : sideB + (size_t)(row0 + r) * 320 + (gk - 320);
                __builtin_amdgcn_global_load_lds((gas_ptr)src, (las_ptr)&As[c * 512], 16, 0, 0);
            }
            stage64(pW1b, nb * 64, 640, k0, Bs, wave, sr, su);
            __syncthreads();
            #pragma unroll
            for (int s = 0; s < 2; ++s) {
                bf16x8 a[2], b[2];
                #pragma unroll
                for (int mf = 0; mf < 2; ++mf) {
                    const int r  = wr * 32 + mf * 16 + (lane & 15);
                    const int lu = (s * 4 + (lane >> 4)) ^ (r & 7);
                    a[mf] = *reinterpret_cast<const bf16x8*>(&As[r * 64 + lu * 8]);
                }
                #pragma unroll
                for (int nf = 0; nf < 2; ++nf) {
                    const int r  = wc * 32 + nf * 16 + (lane & 15);
                    const int lu = (s * 4 + (lane >> 4)) ^ (r & 7);
                    b[nf] = *reinterpret_cast<const bf16x8*>(&Bs[r * 64 + lu * 8]);
                }
                #pragma unroll
                for (int mf = 0; mf < 2; ++mf)
                    #pragma unroll
                    for (int nf = 0; nf < 2; ++nf)
                        acc[mf][nf] = __builtin_amdgcn_mfma_f32_16x16x32_bf16(
                            a[mf], b[nf], acc[mf][nf], 0, 0, 0);
            }
            __syncthreads();
        }
        #pragma unroll
        for (int nf = 0; nf < 2; ++nf) {
            const int col = wc * 32 + nf * 16 + (lane & 15);
            const float bv = pb1[nb * 64 + col];
            #pragma unroll
            for (int mf = 0; mf < 2; ++mf) {
                #pragma unroll
                for (int i = 0; i < 4; ++i) {
                    const int row = wr * 32 + mf * 16 + (lane >> 4) * 4 + i;
                    float v = fmaxf(acc[mf][nf][i] + bv, 0.f);
                    const int u = col >> 3;
                    tpan[nb * 4096 + row * 64 + ((u ^ (row & 7)) * 8) + (col & 7)]
                        = (ushort_t)f2bf(v);
                }
            }
        }
        __syncthreads();
    }

    // phase 2+3: 32-col tiles of pW2 output (160 cols); WM=16 per wave.
    float part[4][3];
    #pragma unroll
    for (int i = 0; i < 4; ++i) { part[i][0] = part[i][1] = part[i][2] = 0.f; }

    for (int ct = 0; ct < 5; ++ct) {
        f32x4 acc[2];
        acc[0] = acc[1] = (f32x4)0.f;
        for (int kt = 0; kt < 5; ++kt) {
            stage32(pW2b, ct * 32, 320, kt * 64, Bs, wave, sr, su);
            __syncthreads();
            #pragma unroll
            for (int s = 0; s < 2; ++s) {
                bf16x8 a, b[2];
                {
                    const int r  = wave * 16 + (lane & 15);
                    const int lu = (s * 4 + (lane >> 4)) ^ (r & 7);
                    a = *reinterpret_cast<const bf16x8*>(&tpan[kt * 4096 + r * 64 + lu * 8]);
                }
                #pragma unroll
                for (int nf = 0; nf < 2; ++nf) {
                    const int r  = nf * 16 + (lane & 15);
                    const int lu = (s * 4 + (lane >> 4)) ^ (r & 7);
                    b[nf] = *reinterpret_cast<const bf16x8*>(&Bs[r * 64 + lu * 8]);
                }
                #pragma unroll
                for (int nf = 0; nf < 2; ++nf)
                    acc[nf] = __builtin_amdgcn_mfma_f32_16x16x32_bf16(a, b[nf], acc[nf], 0, 0, 0);
            }
            __syncthreads();
        }
        #pragma unroll
        for (int nf = 0; nf < 2; ++nf) {
            const int col = ct * 32 + nf * 16 + (lane & 15);
            const float bv = pb2[col];
            #pragma unroll
            for (int i = 0; i < 4; ++i) {
                float v = fmaxf(acc[nf][i] + bv, 0.f);
                #pragma unroll
                for (int n = 0; n < 3; ++n)
                    part[i][n] += v * pW3[n * 160 + col];
            }
        }
    }
    // reduce across the 16 lanes of each (wave, lane>>4) row group
    #pragma unroll
    for (int off = 8; off; off >>= 1)
        #pragma unroll
        for (int i = 0; i < 4; ++i)
            #pragma unroll
            for (int n = 0; n < 3; ++n)
                part[i][n] += __shfl_xor(part[i][n], off, 16);
    if ((lane & 15) == 0) {
        #pragma unroll
        for (int i = 0; i < 4; ++i) {
            const int row = row0 + wave * 16 + (lane >> 4) * 4 + i;
            #pragma unroll
            for (int n = 0; n < 3; ++n)
                out_ref[(size_t)row * 3 + n] = part[i][n] + pb3[n];
        }
    }
}

// fusedD: c1 = relu(mW1 . ao) in regs ; prob = c1 . mW2 + mb2 ; contact rows
__device__ void fusedD_dev(
    int panel, const ushort_t* __restrict__ aoB,
    const ushort_t* __restrict__ mW1b, const float* __restrict__ mb1,
    const float* __restrict__ mW2, const float* __restrict__ mb2,
    float* __restrict__ out_cm, char* smem)
{
    ushort_t* As = (ushort_t*)smem;         // 8 KB
    ushort_t* Bs = As + 4096;               // 4 KB
    float* probs = (float*)(Bs + 2048);     // 64 floats

    const int tid = threadIdx.x, wave = tid >> 6, lane = tid & 63;
    const int row0 = panel * 64;
    const int sr = lane >> 3, su = lane & 7;

    float part[4] = {0.f, 0.f, 0.f, 0.f};

    for (int ct = 0; ct < 5; ++ct) {        // 32-col tiles of mW1 output
        f32x4 acc[2];
        acc[0] = acc[1] = (f32x4)0.f;
        for (int k0 = 0; k0 < 320; k0 += 64) {
            stage64(aoB,  row0,    320, k0, As, wave, sr, su);
            stage32(mW1b, ct * 32, 320, k0, Bs, wave, sr, su);
            __syncthreads();
            #pragma unroll
            for (int s = 0; s < 2; ++s) {
                bf16x8 a, b[2];
                {
                    const int r  = wave * 16 + (lane & 15);
                    const int lu = (s * 4 + (lane >> 4)) ^ (r & 7);
                    a = *reinterpret_cast<const bf16x8*>(&As[r * 64 + lu * 8]);
                }
                #pragma unroll
                for (int nf = 0; nf < 2; ++nf) {
                    const int r  = nf * 16 + (lane & 15);
                    const int lu = (s * 4 + (lane >> 4)) ^ (r & 7);
                    b[nf] = *reinterpret_cast<const bf16x8*>(&Bs[r * 64 + lu * 8]);
                }
                #pragma unroll
                for (int nf = 0; nf < 2; ++nf)
                    acc[nf] = __builtin_amdgcn_mfma_f32_16x16x32_bf16(a, b[nf], acc[nf], 0, 0, 0);
            }
            __syncthreads();
        }
        #pragma unroll
        for (int nf = 0; nf < 2; ++nf) {
            const int col = ct * 32 + nf * 16 + (lane & 15);
            const float bv = mb1[col];
            const float w  = mW2[col];
            #pragma unroll
            for (int i = 0; i < 4; ++i)
                part[i] += fmaxf(acc[nf][i] + bv, 0.f) * w;
        }
    }
    #pragma unroll
    for (int off = 8; off; off >>= 1)
        #pragma unroll
        for (int i = 0; i < 4; ++i)
            part[i] += __shfl_xor(part[i], off, 16);
    if ((lane & 15) == 0) {
        #pragma unroll
        for (int i = 0; i < 4; ++i)
            probs[wave * 16 + (lane >> 4) * 4 + i] = part[i] + mb2[0];
    }
    __syncthreads();

    for (int r = 0; r < 64; ++r) {
        const float p = probs[r];
        reinterpret_cast<float4*>(out_cm + (size_t)(row0 + r) * 1024)[tid] =
            make_float4(p, p, p, p);
    }
}

// ================================ kernels ===================================

struct ConvDesc { const float* src; ushort_t* dst; };
struct ConvPack { ConvDesc d[10]; int start[11]; };

__global__ __launch_bounds__(256) void conv_all(ConvPack p)
{
    const int bid = blockIdx.x;
    int i = 0;
    #pragma unroll
    for (int t = 0; t < 10; ++t) if (bid >= p.start[t + 1]) i = t + 1;
    const int local = bid - p.start[i];
    const int idx = (local * 256 + (int)threadIdx.x) * 4;
    float4 v = *reinterpret_cast<const float4*>(&p.d[i].src[idx]);
    unsigned int lo = f2bf(v.x) | (f2bf(v.y) << 16);
    unsigned int hi = f2bf(v.z) | (f2bf(v.w) << 16);
    *reinterpret_cast<uint2*>(&p.d[i].dst[idx]) = make_uint2(lo, hi);
}

// G1: x -> [fp1(relu) | q | k | v], N=1280 (verified r3)
__global__ __launch_bounds__(256) void k_g1(
    const ushort_t* __restrict__ xb, const ushort_t* __restrict__ Wcat,
    const float* __restrict__ fpb1, const float* __restrict__ bq,
    const float* __restrict__ bk, const float* __restrict__ bvv,
    ushort_t* __restrict__ t1b, ushort_t* __restrict__ qkvb)
{
    __shared__ __align__(16) char smem[24 * 1024];
    const int bid = blockIdx.x;
    const int tx = bid % 20, ty = bid / 20;
    f32x4 acc[4][2];
    #pragma unroll
    for (int i = 0; i < 4; ++i) { acc[i][0] = (f32x4)0.f; acc[i][1] = (f32x4)0.f; }
    gemm_core<64>(tx, ty, xb, xb, 320, 320, Wcat, smem, acc);

    const int tid = threadIdx.x, wave = tid >> 6, lane = tid & 63;
    const int wr = wave >> 1, wc = wave & 1;
    #pragma unroll
    for (int nf = 0; nf < 2; ++nf) {
        const int gn = tx * 64 + wc * 32 + nf * 16 + (lane & 15);
        float bv;
        if      (gn < 320) bv = fpb1[gn];
        else if (gn < 640) bv = bq[gn - 320];
        else if (gn < 960) bv = bk[gn - 640];
        else               bv = bvv[gn - 960];
        #pragma unroll
        for (int mf = 0; mf < 4; ++mf) {
            #pragma unroll
            for (int i = 0; i < 4; ++i) {
                const int gm = ty * 128 + wr * 64 + mf * 16 + (lane >> 4) * 4 + i;
                float v = acc[mf][nf][i] + bv;
                if (gn < 320) t1b [(size_t)gm * 320 + gn] = (ushort_t)f2bf(fmaxf(v, 0.f));
                else          qkvb[(size_t)gm * 960 + gn - 320] = (ushort_t)f2bf(v);
            }
        }
    }
}

// L2: [0,640) G2 (t1 -> fp2 -> bb), [640,8832) attention
__global__ __launch_bounds__(256) void k_g2_attn(
    const ushort_t* __restrict__ t1b, const ushort_t* __restrict__ fpW2b,
    const float* __restrict__ fpb2, float* __restrict__ out_bb,
    ushort_t* __restrict__ bbB,
    const ushort_t* __restrict__ qkvb, ushort_t* __restrict__ ctxb)
{
    __shared__ __align__(16) char smem[24 * 1024];
    const int bid = blockIdx.x;
    if (bid < 640) gemm_full<64, false>(bid, 5, t1b, t1b, 320, 320, fpW2b, fpb2, out_bb, bbB, 320, smem);
    else           attn_dev(bid - 640, qkvb, ctxb, smem);
}

// L3: [0,256) fusedB (bb -> t2 -> side), [256,896) G3 (ctx -> Wo -> ao)
__global__ __launch_bounds__(256) void k_l3(
    const ushort_t* __restrict__ bbB,
    const ushort_t* __restrict__ fpW1b, const float* __restrict__ fpb1,
    const ushort_t* __restrict__ fpW2b, const float* __restrict__ fpb2,
    float* __restrict__ out_side, ushort_t* __restrict__ sideB,
    const ushort_t* __restrict__ ctxb, const ushort_t* __restrict__ Wob,
    const float* __restrict__ bo, ushort_t* __restrict__ aoB)
{
    __shared__ __align__(16) char smem[56 * 1024];
    const int bid = blockIdx.x;
    if (bid < 256) fusedB_dev(bid, bbB, fpW1b, fpb1, fpW2b, fpb2, out_side, sideB, smem);
    else           gemm_full<64, false>(bid - 256, 5, ctxb, ctxb, 320, 320, Wob, bo, nullptr, aoB, 320, smem);
}

// L4: [0,256) fusedC (pW1 -> pW2 -> pW3 -> refined), [256,512) fusedD (contact)
__global__ __launch_bounds__(256) void k_l4(
    const ushort_t* __restrict__ bbB, const ushort_t* __restrict__ sideB,
    const ushort_t* __restrict__ pW1b, const float* __restrict__ pb1,
    const ushort_t* __restrict__ pW2b, const float* __restrict__ pb2,
    const float* __restrict__ pW3, const float* __restrict__ pb3,
    float* __restrict__ out_ref,
    const ushort_t* __restrict__ aoB,
    const ushort_t* __restrict__ mW1b, const float* __restrict__ mb1,
    const float* __restrict__ mW2, const float* __restrict__ mb2,
    float* __restrict__ out_cm)
{
    __shared__ __align__(16) char smem[56 * 1024];
    const int bid = blockIdx.x;
    if (bid < 256) fusedC_dev(bid, bbB, sideB, pW1b, pb1, pW2b, pb2, pW3, pb3, out_ref, smem);
    else           fusedD_dev(bid - 256, aoB, mW1b, mb1, mW2, mb2, out_cm, smem);
}

extern "C" void kernel_launch(void* const* d_in, const int* in_sizes, int n_in,
                              void* d_out, int out_size, void* d_ws, size_t ws_size,
                              hipStream_t stream)
{
    const float* x    = (const float*)d_in[0];
    const float* fpW1 = (const float*)d_in[1];
    const float* fpb1 = (const float*)d_in[2];
    const float* fpW2 = (const float*)d_in[3];
    const float* fpb2 = (const float*)d_in[4];
    const float* Wq   = (const float*)d_in[5];
    const float* bq   = (const float*)d_in[6];
    const float* Wk   = (const float*)d_in[7];
    const float* bk   = (const float*)d_in[8];
    const float* Wv   = (const float*)d_in[9];
    const float* bv   = (const float*)d_in[10];
    const float* Wo   = (const float*)d_in[11];
    const float* bo   = (const float*)d_in[12];
    const float* mW1  = (const float*)d_in[13];
    const float* mb1  = (const float*)d_in[14];
    const float* mW2  = (const float*)d_in[15];
    const float* mb2  = (const float*)d_in[16];
    const float* pW1  = (const float*)d_in[17];
    const float* pb1  = (const float*)d_in[18];
    const float* pW2  = (const float*)d_in[19];
    const float* pb2  = (const float*)d_in[20];
    const float* pW3  = (const float*)d_in[21];
    const float* pb3  = (const float*)d_in[22];

    float* out      = (float*)d_out;
    float* out_bb   = out;
    float* out_side = out + 5242880;
    float* out_cm   = out + 2 * 5242880;
    float* out_ref  = out + 2 * 5242880 + 16777216;

    ushort_t* ws = (ushort_t*)d_ws;
    const size_t BUF = 5242880;
    ushort_t* xb    = ws;              // x bf16; later ctx
    ushort_t* t1b   = ws + 1 * BUF;    // fp1(x) relu
    ushort_t* bbB   = ws + 2 * BUF;
    ushort_t* sideB = ws + 3 * BUF;
    ushort_t* qkvb  = ws + 4 * BUF;    // [M,960] spans 3 BUFs; later aoB
    ushort_t* wb    = ws + 7 * BUF;
    ushort_t* fpW1b = wb;              // Wcat = [fpW1|Wq|Wk|Wv] contiguous
    ushort_t* Wqb   = wb + 102400;
    ushort_t* Wkb   = wb + 204800;
    ushort_t* Wvb   = wb + 307200;
    ushort_t* fpW2b = wb + 409600;
    ushort_t* Wob   = wb + 512000;
    ushort_t* mW1b  = wb + 614400;
    ushort_t* pW1b  = wb + 665600;
    ushort_t* pW2b  = wb + 870400;

    ushort_t* ctxb = xb;               // aliases (lifetimes disjoint)
    ushort_t* aoB  = qkvb;

    dim3 blk(256);

    // L0: fp32 -> bf16 conversions (x + 9 weight matrices)
    ConvPack cp;
    const float* srcs[10] = {x, fpW1, Wq, Wk, Wv, fpW2, Wo, mW1, pW1, pW2};
    ushort_t*    dsts[10] = {xb, fpW1b, Wqb, Wkb, Wvb, fpW2b, Wob, mW1b, pW1b, pW2b};
    const int    nblk[10] = {5120, 100, 100, 100, 100, 100, 100, 50, 200, 50};
    int acc_blk = 0;
    for (int i = 0; i < 10; ++i) {
        cp.d[i].src = srcs[i]; cp.d[i].dst = dsts[i];
        cp.start[i] = acc_blk; acc_blk += nblk[i];
    }
    cp.start[10] = acc_blk;
    conv_all<<<dim3(acc_blk), blk, 0, stream>>>(cp);

    // L1: x -> [fp1 relu | q | k | v]
    k_g1<<<dim3(2560), blk, 0, stream>>>(xb, wb, fpb1, bq, bk, bv, t1b, qkvb);
    // L2: G2 (backbone) || attention
    k_g2_attn<<<dim3(8832), blk, 0, stream>>>(t1b, fpW2b, fpb2, out_bb, bbB, qkvb, ctxb);
    // L3: fusedB (side chain) || G3 (Wo proj)
    k_l3<<<dim3(896), blk, 0, stream>>>(bbB, fpW1b, fpb1, fpW2b, fpb2,
                                        out_side, sideB, ctxb, Wob, bo, aoB);
    // L4: fusedC (refined) || fusedD (contact)
    k_l4<<<dim3(512), blk, 0, stream>>>(bbB, sideB, pW1b, pb1, pW2b, pb2, pW3, pb3,
                                        out_ref, aoB, mW1b, mb1, mW2, mb2, out_cm);
}